// Round 10
// baseline (833.854 us; speedup 1.0000x reference)
//
#include <hip/hip_runtime.h>
#include <stdint.h>

#define NREAL   20000
#define NNODES  20001
#define VN      20000
#define E_EDGES 320000
#define NEXP    80004
#define MPAD    20096   // rows padded to 157*128 for fragment-major buffers
#define NVNW    320     // vn online waves (fused into attn kernel)

typedef unsigned short u16;
typedef unsigned int   u32;
typedef __bf16 bf16x8 __attribute__((ext_vector_type(8)));
typedef float  f32x4  __attribute__((ext_vector_type(4)));
typedef u16    u16x8  __attribute__((ext_vector_type(8)));

// fragment-major layout: element (row, col) of an LD-wide matrix lives at
// (row/16)*(16*LD) + (col/8)*128 + (row%16)*8 + (col%8).
__device__ __host__ __forceinline__ size_t fmoff(int row, int col, int LD) {
    return (size_t)(row >> 4) * ((size_t)LD * 16) + (size_t)((col >> 3) * 128)
         + (size_t)((row & 15) * 8) + (size_t)(col & 7);
}

// qkv column permutation: within one graph's 768 cols [Q|K|V], K/V are
// interleaved at 4-col granularity so dest col 256+8j+r holds K[4j+r] (r<4)
// or V[4j+r-4] (r>=4).  Baked into weights+bias so the GEMM stores contiguously.
__device__ __forceinline__ int qkv_perm(int n) {  // n in [0,768) source -> dest
    if (n < 256) return n;
    int u = n - 256;
    int part = u >> 8;        // 0 = K, 1 = V
    int cl = u & 255;
    return 256 + (cl >> 2) * 8 + part * 4 + (cl & 3);
}

__device__ __forceinline__ float bf2f(u16 v) {
    union { u32 u; float f; } x; x.u = ((u32)v) << 16; return x.f;
}
__device__ __forceinline__ u16 f2bf(float f) {
    union { float f; u32 u; } x; x.f = f;
    u32 r = (x.u + 0x7fffu + ((x.u >> 16) & 1u)) >> 16;
    return (u16)r;
}
__device__ __forceinline__ float4 cvt4(ushort4 u) {
    return make_float4(bf2f(u.x), bf2f(u.y), bf2f(u.z), bf2f(u.w));
}
__device__ __forceinline__ float4 ld4bf(const u16* p) { return cvt4(*(const ushort4*)p); }
// interleaved kv row: per 8-u16 chunk = [k0 k1 k2 k3 | v0 v1 v2 v3]
__device__ __forceinline__ float4 cvtk8(u16x8 r) {
    return make_float4(bf2f(r[0]), bf2f(r[1]), bf2f(r[2]), bf2f(r[3]));
}
__device__ __forceinline__ float4 cvtv8(u16x8 r) {
    return make_float4(bf2f(r[4]), bf2f(r[5]), bf2f(r[6]), bf2f(r[7]));
}

// ---------------- setup kernels ----------------

__global__ void hinit_kernel(const float* __restrict__ x, float* __restrict__ h,
                             u16* __restrict__ hb) {
    int idx = blockIdx.x * 256 + threadIdx.x;
    if (idx >= NNODES * 64) return;
    int row = idx >> 6, c0 = (idx & 63) * 4;
    float4 v = make_float4(0.f, 0.f, 0.f, 0.f);
    if (row < NREAL) v = *(const float4*)(x + (size_t)row * 256 + c0);
    *(float4*)(h + (size_t)row * 256 + c0) = v;
    ushort4 o;
    o.x = f2bf(v.x); o.y = f2bf(v.y); o.z = f2bf(v.z); o.w = f2bf(v.w);
    *(ushort4*)(hb + fmoff(row, c0, 256)) = o;
}

__global__ void init_kernel(int* cnt, int* fill, int* ecnt,
                            const float* __restrict__ bl, const float* __restrict__ be,
                            float* __restrict__ bcat,
                            const float* __restrict__ bol, const float* __restrict__ boe,
                            float* __restrict__ bsum) {
    int i = blockIdx.x * 256 + threadIdx.x;
    if (i < NREAL) { cnt[i] = 0; fill[i] = 0; }
    if (i < NNODES) ecnt[i] = 0;
    if (i < 3 * 1536) {
        int l = i / 1536, c = i - l * 1536;   // source col
        float v = (c < 768) ? bl[l * 768 + c] : be[l * 768 + c - 768];
        int cc = (c >= 768) ? c - 768 : c;
        int d = qkv_perm(cc) + ((c >= 768) ? 768 : 0);
        bcat[l * 1536 + d] = v;
    }
    if (i < 3 * 256) bsum[i] = bol[i] + boe[i];
}

__global__ void csr_count_kernel(const int* __restrict__ ei, int* __restrict__ cnt) {
    int e = blockIdx.x * 256 + threadIdx.x;
    if (e < E_EDGES) atomicAdd(&cnt[ei[E_EDGES + e]], 1);
}

__global__ void csr_scan_kernel(const int* __restrict__ cnt, int* __restrict__ indptr) {
    __shared__ int ssum[256];
    int t = threadIdx.x;
    int c0 = t * 79;
    int s = 0;
    for (int j = 0; j < 79; j++) {
        int i = c0 + j;
        if (i < NREAL) s += cnt[i];
    }
    ssum[t] = s;
    __syncthreads();
    for (int d2 = 1; d2 < 256; d2 <<= 1) {
        int v = (t >= d2) ? ssum[t - d2] : 0;
        __syncthreads();
        ssum[t] += v;
        __syncthreads();
    }
    int run = (t == 0) ? 0 : ssum[t - 1];
    for (int j = 0; j < 79; j++) {
        int i = c0 + j;
        if (i < NREAL) { indptr[i] = run; run += cnt[i]; }
    }
    if (t == 255) indptr[NREAL] = run;
}

__global__ void csr_scatter_kernel(const int* __restrict__ ei, const int* __restrict__ indptr,
                                   int* __restrict__ fill, int* __restrict__ srcs) {
    int e = blockIdx.x * 256 + threadIdx.x;
    if (e < E_EDGES) {
        int d = ei[E_EDGES + e];
        int pos = indptr[d] + atomicAdd(&fill[d], 1);
        srcs[pos] = ei[e];
    }
}

__global__ void exp_scatter_kernel(const int* __restrict__ eei, int* __restrict__ ecnt,
                                   int* __restrict__ esrcs) {
    int e = blockIdx.x * 256 + threadIdx.x;
    if (e < NEXP) {
        int d = eei[NEXP + e];
        int pos = atomicAdd(&ecnt[d], 1);
        esrcs[d * 4 + pos] = eei[e];
    }
}

// ALL weights -> bf16 fragment-major, one launch. Per-layer slab 1048576 u16:
// [0] WqkvL(FM 768x256, cols k/v-interleave-permuted) [196608] WqkvE (same perm)
// [393216] Wo-cat FM(256 x 512) (K-stacked WoL;WoE)
// [524288] W1 FM(1024x256) [786432] W2 FM(256x1024)
__global__ void wconv_all_kernel(const float* __restrict__ WqkvL, const float* __restrict__ WqkvE,
                                 const float* __restrict__ WoL, const float* __restrict__ WoE,
                                 const float* __restrict__ W1, const float* __restrict__ W2,
                                 u16* __restrict__ out) {
    int i = blockIdx.x * 256 + threadIdx.x;
    if (i >= 3 * 1048576) return;
    int l = i / 1048576, r = i - l * 1048576;
    if (r >= 393216 && r < 524288) {
        // Wo-cat: r2 = k*256 + n, k in [0,512), n in [0,256)
        int r2 = r - 393216;
        int k = r2 >> 8, n = r2 & 255;
        float v = (k < 256) ? WoL[(size_t)l * 65536 + k * 256 + n]
                            : WoE[(size_t)l * 65536 + (k - 256) * 256 + n];
        out[(size_t)l * 1048576 + 393216 + fmoff(n, k, 512)] = f2bf(v);
        return;
    }
    const float* src; int K, N; int base;
    if (r < 196608)      { src = WqkvL; K = 256;  N = 768;  base = 0; }
    else if (r < 393216) { src = WqkvE; K = 256;  N = 768;  base = 196608; }
    else if (r < 786432) { src = W1;    K = 256;  N = 1024; base = 524288; }
    else                 { src = W2;    K = 1024; N = 256;  base = 786432; }
    int r2 = r - base;
    int k = r2 / N, n = r2 - k * N;
    int d = (r < 393216) ? qkv_perm(n) : n;   // bake kv interleave into qkv weights
    out[(size_t)l * 1048576 + base + fmoff(d, k, K)] = f2bf(src[(size_t)l * K * N + r2]);
}

// ---------------- qkv GEMM (K=256): 32x256 block, 4 waves, depth-3 prefetch ----
// wave w: 32 rows x 64 cols (2x4 frags); 3768 blocks (~15 waves/CU in flight).
// Same ascending-K accumulation order as before -> bitwise-identical outputs.
__global__ __launch_bounds__(256) void qkv_rw(
    const u16* __restrict__ A, const u16* __restrict__ Bt, const float* __restrict__ bias,
    u16* __restrict__ Q0, u16* __restrict__ KV0,
    u16* __restrict__ Q1, u16* __restrict__ KV1, int M) {
    const int lin = blockIdx.x;
    const int mt = lin / 6, ns = lin - mt * 6;
    const int tm = mt * 32;
    if (tm >= M) return;
    const int tid = threadIdx.x;
    const int w = tid >> 6, lane = tid & 63;
    const int lm = lane & 15, q = lane >> 4;

    f32x4 acc[2][4];
#pragma unroll
    for (int a = 0; a < 2; a++)
#pragma unroll
        for (int b = 0; b < 4; b++) acc[a][b] = (f32x4)0.0f;

    const u16* apf[2];
    const u16* bpf[4];
#pragma unroll
    for (int mi = 0; mi < 2; mi++)
        apf[mi] = A + (size_t)(tm / 16 + mi) * 4096 + q * 128 + lm * 8;
#pragma unroll
    for (int ni = 0; ni < 4; ni++)
        bpf[ni] = Bt + (size_t)(ns * 16 + w * 4 + ni) * 4096 + q * 128 + lm * 8;

    bf16x8 sA[4][2], sB[4][4];
#pragma unroll
    for (int s = 0; s < 3; s++) {
#pragma unroll
        for (int mi = 0; mi < 2; mi++) sA[s][mi] = *(const bf16x8*)(apf[mi] + s * 512);
#pragma unroll
        for (int ni = 0; ni < 4; ni++) sB[s][ni] = *(const bf16x8*)(bpf[ni] + s * 512);
    }
#pragma unroll
    for (int i = 0; i < 8; i++) {
        const int cu = i & 3, pf = (i + 3) & 3;
        if (i + 3 < 8) {
#pragma unroll
            for (int mi = 0; mi < 2; mi++) sA[pf][mi] = *(const bf16x8*)(apf[mi] + (i + 3) * 512);
#pragma unroll
            for (int ni = 0; ni < 4; ni++) sB[pf][ni] = *(const bf16x8*)(bpf[ni] + (i + 3) * 512);
        }
#pragma unroll
        for (int mi = 0; mi < 2; mi++)
#pragma unroll
            for (int ni = 0; ni < 4; ni++)
                acc[mi][ni] = __builtin_amdgcn_mfma_f32_16x16x32_bf16(
                    sB[cu][ni], sA[cu][mi], acc[mi][ni], 0, 0, 0);
    }

    float4 b4[4];
#pragma unroll
    for (int ni = 0; ni < 4; ni++)
        b4[ni] = *(const float4*)(bias + ns * 256 + w * 64 + ni * 16 + q * 4);

#pragma unroll
    for (int mi = 0; mi < 2; mi++) {
        int grow = tm + mi * 16 + lm;
        if (grow >= M) continue;
#pragma unroll
        for (int ni = 0; ni < 4; ni++) {
            int gcol = ns * 256 + w * 64 + ni * 16 + q * 4;
            float v0 = acc[mi][ni][0] + b4[ni].x;
            float v1 = acc[mi][ni][1] + b4[ni].y;
            float v2 = acc[mi][ni][2] + b4[ni].z;
            float v3 = acc[mi][ni][3] + b4[ni].w;
            ushort4 o;
            o.x = f2bf(v0); o.y = f2bf(v1); o.z = f2bf(v2); o.w = f2bf(v3);
            u16* dst;
            if (gcol < 256)       dst = Q0  + (size_t)grow * 256 + gcol;
            else if (gcol < 768)  dst = KV0 + (size_t)grow * 512 + (gcol - 256);
            else if (gcol < 1024) dst = Q1  + (size_t)grow * 256 + (gcol - 768);
            else                  dst = KV1 + (size_t)grow * 512 + (gcol - 1024);
            *(ushort4*)dst = o;
        }
    }
}

// ---------------- fused FFN (W1+gelu+W2+resid), 16KB LDS chunk streaming --------
// Block = 32 rows x 256 out-cols; 628 blocks.  4 chunks of 256 mid-cols:
//   phase 1: mid_chunk = gelu(h @ W1[:,chunk] + b1)  -> LDS (FM 32x256, 16KB)
//   phase 2: acc2 += mid_chunk @ W2[chunk,:]          (A from LDS, ~12cyc reads)
// Eliminates the 41MB mid write + 41MB read per layer and one dispatch drain.
// Ascending-k accumulation per output element identical to old ffn1_rw + w2_rw
// -> bitwise-identical results.
__global__ __launch_bounds__(256) void ffn_fused(
    const u16* __restrict__ A, const u16* __restrict__ W1t, const u16* __restrict__ W2t,
    const float* __restrict__ b1v, const float* __restrict__ b2v,
    const float* __restrict__ resid, float* __restrict__ Cf, u16* __restrict__ Cb,
    int last, int M) {
    __shared__ u16 smid[32 * 256];   // 16 KB
    const int tm = blockIdx.x * 32;
    if (tm >= M) return;
    const int tid = threadIdx.x;
    const int w = tid >> 6, lane = tid & 63;
    const int lm = lane & 15, q = lane >> 4;

    f32x4 acc2[2][4];
#pragma unroll
    for (int a = 0; a < 2; a++)
#pragma unroll
        for (int b = 0; b < 4; b++) acc2[a][b] = (f32x4)0.0f;

    const u16* apf[2];
#pragma unroll
    for (int mi = 0; mi < 2; mi++)
        apf[mi] = A + (size_t)(tm / 16 + mi) * 4096 + q * 128 + lm * 8;
    const u16* bpf2[4];
#pragma unroll
    for (int ni = 0; ni < 4; ni++)
        bpf2[ni] = W2t + (size_t)(w * 4 + ni) * 16384 + q * 128 + lm * 8;
    const u16* alds[2];
#pragma unroll
    for (int mi = 0; mi < 2; mi++)
        alds[mi] = smid + mi * 4096 + q * 128 + lm * 8;

    for (int c = 0; c < 4; c++) {
        // ---- phase 1: mid chunk = gelu(h @ W1[:, c*256..] + b1) ----
        f32x4 acc1[2][4];
#pragma unroll
        for (int a = 0; a < 2; a++)
#pragma unroll
            for (int b = 0; b < 4; b++) acc1[a][b] = (f32x4)0.0f;
        const u16* bpf1[4];
#pragma unroll
        for (int ni = 0; ni < 4; ni++)
            bpf1[ni] = W1t + (size_t)(c * 16 + w * 4 + ni) * 4096 + q * 128 + lm * 8;

        {
            bf16x8 sA[3][2], sB[3][4];
#pragma unroll
            for (int s = 0; s < 2; s++) {
#pragma unroll
                for (int mi = 0; mi < 2; mi++) sA[s][mi] = *(const bf16x8*)(apf[mi] + s * 512);
#pragma unroll
                for (int ni = 0; ni < 4; ni++) sB[s][ni] = *(const bf16x8*)(bpf1[ni] + s * 512);
            }
#pragma unroll
            for (int i = 0; i < 8; i++) {
                const int cu = i % 3, pf = (i + 2) % 3;
                if (i + 2 < 8) {
#pragma unroll
                    for (int mi = 0; mi < 2; mi++)
                        sA[pf][mi] = *(const bf16x8*)(apf[mi] + (i + 2) * 512);
#pragma unroll
                    for (int ni = 0; ni < 4; ni++)
                        sB[pf][ni] = *(const bf16x8*)(bpf1[ni] + (i + 2) * 512);
                }
#pragma unroll
                for (int mi = 0; mi < 2; mi++)
#pragma unroll
                    for (int ni = 0; ni < 4; ni++)
                        acc1[mi][ni] = __builtin_amdgcn_mfma_f32_16x16x32_bf16(
                            sB[cu][ni], sA[cu][mi], acc1[mi][ni], 0, 0, 0);
            }
        }
        // bias + gelu -> LDS (identical values to old ffn1_rw's mid)
        float4 b4[4];
#pragma unroll
        for (int ni = 0; ni < 4; ni++)
            b4[ni] = *(const float4*)(b1v + c * 256 + w * 64 + ni * 16 + q * 4);
#pragma unroll
        for (int mi = 0; mi < 2; mi++) {
#pragma unroll
            for (int ni = 0; ni < 4; ni++) {
                int lrow = mi * 16 + lm;
                int lcol = w * 64 + ni * 16 + q * 4;
                float v0 = acc1[mi][ni][0] + b4[ni].x;
                float v1 = acc1[mi][ni][1] + b4[ni].y;
                float v2 = acc1[mi][ni][2] + b4[ni].z;
                float v3 = acc1[mi][ni][3] + b4[ni].w;
                float g0, g1, g2, g3;
                {
                    float u = 0.7978845608f * (v0 + 0.044715f * v0 * v0 * v0);
                    g0 = 0.5f * v0 * (2.0f - 2.0f / (__expf(2.0f * u) + 1.0f));
                }
                {
                    float u = 0.7978845608f * (v1 + 0.044715f * v1 * v1 * v1);
                    g1 = 0.5f * v1 * (2.0f - 2.0f / (__expf(2.0f * u) + 1.0f));
                }
                {
                    float u = 0.7978845608f * (v2 + 0.044715f * v2 * v2 * v2);
                    g2 = 0.5f * v2 * (2.0f - 2.0f / (__expf(2.0f * u) + 1.0f));
                }
                {
                    float u = 0.7978845608f * (v3 + 0.044715f * v3 * v3 * v3);
                    g3 = 0.5f * v3 * (2.0f - 2.0f / (__expf(2.0f * u) + 1.0f));
                }
                ushort4 o;
                o.x = f2bf(g0); o.y = f2bf(g1); o.z = f2bf(g2); o.w = f2bf(g3);
                *(ushort4*)(smid + fmoff(lrow, lcol, 256)) = o;
            }
        }
        __syncthreads();

        // ---- phase 2: acc2 += mid_chunk @ W2[c*256.., :] (A from LDS) ----
        {
            bf16x8 tB[3][4];
#pragma unroll
            for (int s = 0; s < 2; s++)
#pragma unroll
                for (int ni = 0; ni < 4; ni++)
                    tB[s][ni] = *(const bf16x8*)(bpf2[ni] + (c * 8 + s) * 512);
#pragma unroll
            for (int i = 0; i < 8; i++) {
                const int cu = i % 3, pf = (i + 2) % 3;
                if (i + 2 < 8) {
#pragma unroll
                    for (int ni = 0; ni < 4; ni++)
                        tB[pf][ni] = *(const bf16x8*)(bpf2[ni] + (c * 8 + i + 2) * 512);
                }
                bf16x8 a0 = *(const bf16x8*)(alds[0] + i * 512);
                bf16x8 a1 = *(const bf16x8*)(alds[1] + i * 512);
#pragma unroll
                for (int ni = 0; ni < 4; ni++) {
                    acc2[0][ni] = __builtin_amdgcn_mfma_f32_16x16x32_bf16(
                        tB[cu][ni], a0, acc2[0][ni], 0, 0, 0);
                    acc2[1][ni] = __builtin_amdgcn_mfma_f32_16x16x32_bf16(
                        tB[cu][ni], a1, acc2[1][ni], 0, 0, 0);
                }
            }
        }
        __syncthreads();   // before next chunk overwrites LDS
    }

    // epilogue: + b2 + resid (same FP order as old w2_rw)
    float4 c4[4];
#pragma unroll
    for (int ni = 0; ni < 4; ni++)
        c4[ni] = *(const float4*)(b2v + w * 64 + ni * 16 + q * 4);

#pragma unroll
    for (int mi = 0; mi < 2; mi++) {
        int grow = tm + mi * 16 + lm;
        if (grow >= (last ? NREAL : M)) continue;
#pragma unroll
        for (int ni = 0; ni < 4; ni++) {
            int gcol = w * 64 + ni * 16 + q * 4;
            float v0 = acc2[mi][ni][0] + c4[ni].x;
            float v1 = acc2[mi][ni][1] + c4[ni].y;
            float v2 = acc2[mi][ni][2] + c4[ni].z;
            float v3 = acc2[mi][ni][3] + c4[ni].w;
            size_t idx = (size_t)grow * 256 + gcol;
            float4 rv = *(const float4*)(resid + idx);
            float o0 = rv.x + v0, o1 = rv.y + v1, o2 = rv.z + v2, o3 = rv.w + v3;
            *(float4*)(Cf + idx) = make_float4(o0, o1, o2, o3);
            if (!last) {
                ushort4 o;
                o.x = f2bf(o0); o.y = f2bf(o1); o.z = f2bf(o2); o.w = f2bf(o3);
                *(ushort4*)(Cb + fmoff(grow, gcol, 256)) = o;
            }
        }
    }
}

// ---------------- Wo GEMM + residual + LayerNorm (K=512), depth-3 prefetch ------
// 32 rows x 256 cols per block, 4 waves; 628 blocks.  Block VN/32 first performs
// the vn partial merge -- barriers order the acat write before its own A-loads.
__global__ __launch_bounds__(256) void wo_ln_rw(
    const u16* A, const u16* __restrict__ Bt, const float* __restrict__ bias,
    const float* __restrict__ resid, const float* __restrict__ g,
    const float* __restrict__ bvec, float* __restrict__ hout, u16* __restrict__ hb,
    const float* __restrict__ part, u16* acat_w, int M) {
    __shared__ float smS[32][4];
    __shared__ float smQ[32][4];
    const int tm = blockIdx.x * 32;
    if (tm >= M) return;
    const int tid = threadIdx.x;
    const int w = tid >> 6, lane = tid & 63;
    const int lm = lane & 15, q = lane >> 4;

    if (blockIdx.x == VN / 32) {
        // vn partial merge: 4 waves x 80 partials + cross-wave LDS combine
        __shared__ float smm[4][64][6];
        int hh = lane >> 4;
        int ov = (hh << 6) + (lane & 15) * 4;
        float mm = -1e30f, ll = 0.0f;
        float ax = 0, ay = 0, az = 0, aw = 0;
        for (int p = w * 80; p < w * 80 + 80; p++) {
            const float* pp = part + (size_t)p * 264;
            float pm = pp[hh], pl = pp[4 + hh];
            float4 nm = *(const float4*)(pp + 8 + ov);
            float Mn = fmaxf(mm, pm);
            float s0 = __expf(mm - Mn);
            float s1 = __expf(pm - Mn);
            ax = ax * s0 + nm.x * s1;
            ay = ay * s0 + nm.y * s1;
            az = az * s0 + nm.z * s1;
            aw = aw * s0 + nm.w * s1;
            ll = ll * s0 + pl * s1;
            mm = Mn;
        }
        smm[w][lane][0] = mm; smm[w][lane][1] = ll;
        smm[w][lane][2] = ax; smm[w][lane][3] = ay;
        smm[w][lane][4] = az; smm[w][lane][5] = aw;
        __syncthreads();
        if (w == 0) {
            float M2 = -1e30f, L2 = 0.0f;
            float bx = 0, by = 0, bz = 0, bw = 0;
#pragma unroll
            for (int p = 0; p < 4; p++) {
                float pm = smm[p][lane][0], pl = smm[p][lane][1];
                float Mn = fmaxf(M2, pm);
                float s0 = __expf(M2 - Mn);
                float s1 = __expf(pm - Mn);
                bx = bx * s0 + smm[p][lane][2] * s1;
                by = by * s0 + smm[p][lane][3] * s1;
                bz = bz * s0 + smm[p][lane][4] * s1;
                bw = bw * s0 + smm[p][lane][5] * s1;
                L2 = L2 * s0 + pl * s1;
                M2 = Mn;
            }
            float inv = 1.0f / (L2 + 1e-16f);
            ushort4 o;
            o.x = f2bf(bx * inv); o.y = f2bf(by * inv);
            o.z = f2bf(bz * inv); o.w = f2bf(bw * inv);
            *(ushort4*)(acat_w + fmoff(VN, ov, 512)) = o;
        }
        __syncthreads();
    }

    f32x4 acc[2][4];
#pragma unroll
    for (int a = 0; a < 2; a++)
#pragma unroll
        for (int b = 0; b < 4; b++) acc[a][b] = (f32x4)0.0f;

    const u16* apf[2];
    const u16* bpf[4];
#pragma unroll
    for (int mi = 0; mi < 2; mi++)
        apf[mi] = A + (size_t)(tm / 16 + mi) * 8192 + q * 128 + lm * 8;
#pragma unroll
    for (int ni = 0; ni < 4; ni++)
        bpf[ni] = Bt + (size_t)(w * 4 + ni) * 8192 + q * 128 + lm * 8;

    bf16x8 sA[4][2], sB[4][4];
#pragma unroll
    for (int s = 0; s < 3; s++) {
#pragma unroll
        for (int mi = 0; mi < 2; mi++) sA[s][mi] = *(const bf16x8*)(apf[mi] + s * 512);
#pragma unroll
        for (int ni = 0; ni < 4; ni++) sB[s][ni] = *(const bf16x8*)(bpf[ni] + s * 512);
    }
#pragma unroll
    for (int i = 0; i < 16; i++) {
        const int cu = i & 3, pf = (i + 3) & 3;
        if (i + 3 < 16) {
#pragma unroll
            for (int mi = 0; mi < 2; mi++) sA[pf][mi] = *(const bf16x8*)(apf[mi] + (i + 3) * 512);
#pragma unroll
            for (int ni = 0; ni < 4; ni++) sB[pf][ni] = *(const bf16x8*)(bpf[ni] + (i + 3) * 512);
        }
#pragma unroll
        for (int mi = 0; mi < 2; mi++)
#pragma unroll
            for (int ni = 0; ni < 4; ni++)
                acc[mi][ni] = __builtin_amdgcn_mfma_f32_16x16x32_bf16(
                    sB[cu][ni], sA[cu][mi], acc[mi][ni], 0, 0, 0);
    }

    // v = resid + (acc + bias)
    float4 b4[4];
#pragma unroll
    for (int ni = 0; ni < 4; ni++)
        b4[ni] = *(const float4*)(bias + w * 64 + ni * 16 + q * 4);
#pragma unroll
    for (int mi = 0; mi < 2; mi++) {
        int grow = tm + mi * 16 + lm;
#pragma unroll
        for (int ni = 0; ni < 4; ni++) {
            int gcol = w * 64 + ni * 16 + q * 4;
            size_t idx = (size_t)grow * 256 + gcol;
            float4 rv = *(const float4*)(resid + idx);  // OOB rows read scratch (safe)
            acc[mi][ni][0] = rv.x + (acc[mi][ni][0] + b4[ni].x);
            acc[mi][ni][1] = rv.y + (acc[mi][ni][1] + b4[ni].y);
            acc[mi][ni][2] = rv.z + (acc[mi][ni][2] + b4[ni].z);
            acc[mi][ni][3] = rv.w + (acc[mi][ni][3] + b4[ni].w);
        }
    }

    // LayerNorm over each row's 256 cols (4 waves x 64 cols, LDS cross-wave)
    float s1[2];
#pragma unroll
    for (int mi = 0; mi < 2; mi++) {
        float s = 0.f;
#pragma unroll
        for (int ni = 0; ni < 4; ni++)
            s += acc[mi][ni][0] + acc[mi][ni][1] + acc[mi][ni][2] + acc[mi][ni][3];
        s += __shfl_xor(s, 16); s += __shfl_xor(s, 32);
        s1[mi] = s;
    }
    if (lane < 16) {
        smS[lm][w] = s1[0];
        smS[16 + lm][w] = s1[1];
    }
    __syncthreads();
    float mu[2];
#pragma unroll
    for (int mi = 0; mi < 2; mi++) {
        int r = mi * 16 + lm;
        mu[mi] = (smS[r][0] + smS[r][1] + smS[r][2] + smS[r][3]) * (1.0f / 256.0f);
    }
    float s2[2];
#pragma unroll
    for (int mi = 0; mi < 2; mi++) {
        float s = 0.f;
#pragma unroll
        for (int ni = 0; ni < 4; ni++) {
            float d0 = acc[mi][ni][0] - mu[mi];
            float d1 = acc[mi][ni][1] - mu[mi];
            float d2 = acc[mi][ni][2] - mu[mi];
            float d3 = acc[mi][ni][3] - mu[mi];
            s += d0 * d0 + d1 * d1 + d2 * d2 + d3 * d3;
        }
        s += __shfl_xor(s, 16); s += __shfl_xor(s, 32);
        s2[mi] = s;
    }
    if (lane < 16) {
        smQ[lm][w] = s2[0];
        smQ[16 + lm][w] = s2[1];
    }
    __syncthreads();
    float rinv[2];
#pragma unroll
    for (int mi = 0; mi < 2; mi++) {
        int r = mi * 16 + lm;
        float var = (smQ[r][0] + smQ[r][1] + smQ[r][2] + smQ[r][3]) * (1.0f / 256.0f);
        rinv[mi] = 1.0f / sqrtf(var + 1e-5f);
    }
#pragma unroll
    for (int mi = 0; mi < 2; mi++) {
        int grow = tm + mi * 16 + lm;
        if (grow >= M) continue;
#pragma unroll
        for (int ni = 0; ni < 4; ni++) {
            int gcol = w * 64 + ni * 16 + q * 4;
            float4 gv = *(const float4*)(g + gcol);
            float4 bv = *(const float4*)(bvec + gcol);
            float4 y;
            y.x = (acc[mi][ni][0] - mu[mi]) * rinv[mi] * gv.x + bv.x;
            y.y = (acc[mi][ni][1] - mu[mi]) * rinv[mi] * gv.y + bv.y;
            y.z = (acc[mi][ni][2] - mu[mi]) * rinv[mi] * gv.z + bv.z;
            y.w = (acc[mi][ni][3] - mu[mi]) * rinv[mi] * gv.w + bv.w;
            *(float4*)(hout + (size_t)grow * 256 + gcol) = y;
            ushort4 o;
            o.x = f2bf(y.x); o.y = f2bf(y.y); o.z = f2bf(y.z); o.w = f2bf(y.w);
            *(ushort4*)(hb + fmoff(grow, gcol, 256)) = o;
        }
    }
}

// ---------------- fused attention (vn partials + local + expander) ---------------
// kv rows are interleaved: chunk j (16B) = [k[4j..4j+3] | v[4j..4j+3]] -> one
// dwordx4 per lane per edge.  gw layout: [0,NVNW) vn partial waves,
// [NVNW, NVNW+NREAL) local nodes, [.., +NNODES) expander nodes.
__global__ void attn_fused_kernel(const u16* __restrict__ qb_loc, const u16* __restrict__ kv_loc,
                                  const u16* __restrict__ qb_exp, const u16* __restrict__ kv_exp,
                                  const int* __restrict__ indptr, const int* __restrict__ srcs,
                                  const int* __restrict__ esrcs,
                                  u16* __restrict__ acat, float* __restrict__ part) {
    int gw0 = (int)((blockIdx.x * (size_t)blockDim.x + threadIdx.x) >> 6);
    int gw = __builtin_amdgcn_readfirstlane(gw0);   // wave-uniform -> SGPR control flow
    int lane = threadIdx.x & 63;
    int h = lane >> 4;
    int off = (h << 6) + (lane & 15) * 4;   // u16 col in a 256-wide q row
    int coff = (off >> 2) * 8;              // u16 offset of interleaved 16B chunk

    if (gw < NVNW) {
        // vn dense attention: single-pass online partial
        int wv = gw;
        float4 qv = ld4bf(qb_loc + (size_t)VN * 256 + off);
        float m = -1e30f, l = 0.0f;
        float ax = 0, ay = 0, az = 0, aw = 0;
        for (int i = wv; i < NREAL; i += NVNW) {
            u16x8 r = *(const u16x8*)(kv_loc + (size_t)i * 512 + coff);
            float4 k4 = cvtk8(r);
            float4 v4 = cvtv8(r);
            float s = qv.x * k4.x + qv.y * k4.y + qv.z * k4.z + qv.w * k4.w;
            s += __shfl_xor(s, 1); s += __shfl_xor(s, 2);
            s += __shfl_xor(s, 4); s += __shfl_xor(s, 8);
            float sc = s * 0.125f;
            float mn = fmaxf(m, sc);
            float fold = __expf(m - mn);
            float ee = __expf(sc - mn);
            ax = ax * fold + v4.x * ee;
            ay = ay * fold + v4.y * ee;
            az = az * fold + v4.z * ee;
            aw = aw * fold + v4.w * ee;
            l = l * fold + ee;
            m = mn;
        }
        float* pp = part + (size_t)wv * 264;
        if ((lane & 15) == 0) { pp[h] = m; pp[4 + h] = l; }
        *(float4*)(pp + 8 + off) = make_float4(ax, ay, az, aw);
        return;
    }
    gw -= NVNW;

    const u16 *qb, *kv;
    const int* sl;
    int node, beg, deg, tot, cbase;
    if (gw < NREAL) {
        node = gw; qb = qb_loc; kv = kv_loc; sl = srcs; cbase = 0;
        beg = indptr[node]; deg = indptr[node + 1] - beg; tot = deg + 1;  // +vn edge
    } else if (gw < NREAL + NNODES) {
        node = gw - NREAL;
        qb = qb_exp; kv = kv_exp; sl = esrcs; cbase = 256;
        beg = node * 4; deg = 4; tot = 4;
    } else {
        return;
    }

    float4 qv = ld4bf(qb + (size_t)node * 256 + off);
    float m = -1e30f, l = 0.0f;
    float ax = 0, ay = 0, az = 0, aw = 0;

    if (tot <= 4) {
        u16x8 raw[4];
#pragma unroll
        for (int j = 0; j < 4; j++) {
            int s = (j < deg) ? sl[beg + j] : VN;
            raw[j] = *(const u16x8*)(kv + (size_t)s * 512 + coff);
        }
        float sc[4];
#pragma unroll
        for (int j = 0; j < 4; j++) {
            float4 k4 = cvtk8(raw[j]);
            float p = qv.x * k4.x + qv.y * k4.y + qv.z * k4.z + qv.w * k4.w;
            p += __shfl_xor(p, 1); p += __shfl_xor(p, 2);
            p += __shfl_xor(p, 4); p += __shfl_xor(p, 8);
            sc[j] = (j < tot) ? p * 0.125f : -1e30f;
        }
        float mn = fmaxf(fmaxf(sc[0], sc[1]), fmaxf(sc[2], sc[3]));
#pragma unroll
        for (int j = 0; j < 4; j++) {
            float ee = __expf(sc[j] - mn);
            float4 v4 = cvtv8(raw[j]);
            ax += v4.x * ee; ay += v4.y * ee; az += v4.z * ee; aw += v4.w * ee;
            l += ee;
        }
        m = mn;
    } else {
        // double-buffered 8-edge chunks: prefetch chunk c+1 while processing c
        const int nch = (tot + 7) >> 3;
        u16x8 rA[8], rB[8];
#pragma unroll
        for (int j = 0; j < 8; j++) {
            int s = (j < deg) ? sl[beg + j] : VN;
            rA[j] = *(const u16x8*)(kv + (size_t)s * 512 + coff);
        }
        for (int c = 0; c < nch; c++) {
            if (c + 1 < nch) {
                const int e0n = (c + 1) * 8;
#pragma unroll
                for (int j = 0; j < 8; j++) {
                    int e = e0n + j;
                    int s = (e < deg) ? sl[beg + e] : VN;
                    rB[j] = *(const u16x8*)(kv + (size_t)s * 512 + coff);
                }
            }
            const int e0 = c * 8;
            float sc[8];
#pragma unroll
            for (int j = 0; j < 8; j++) {
                float4 k4 = cvtk8(rA[j]);
                float p = qv.x * k4.x + qv.y * k4.y + qv.z * k4.z + qv.w * k4.w;
                p += __shfl_xor(p, 1); p += __shfl_xor(p, 2);
                p += __shfl_xor(p, 4); p += __shfl_xor(p, 8);
                sc[j] = (e0 + j < tot) ? p * 0.125f : -1e30f;
            }
            float cmax = fmaxf(fmaxf(fmaxf(sc[0], sc[1]), fmaxf(sc[2], sc[3])),
                               fmaxf(fmaxf(sc[4], sc[5]), fmaxf(sc[6], sc[7])));
            float mn = fmaxf(m, cmax);
            float fold = __expf(m - mn);
            ax *= fold; ay *= fold; az *= fold; aw *= fold; l *= fold;
#pragma unroll
            for (int j = 0; j < 8; j++) {
                float ee = __expf(sc[j] - mn);
                float4 v4 = cvtv8(rA[j]);
                ax += v4.x * ee; ay += v4.y * ee; az += v4.z * ee; aw += v4.w * ee;
                l += ee;
            }
            m = mn;
#pragma unroll
            for (int j = 0; j < 8; j++) rA[j] = rB[j];
        }
    }
    float inv = 1.0f / (l + 1e-16f);
    ushort4 o;
    o.x = f2bf(ax * inv); o.y = f2bf(ay * inv);
    o.z = f2bf(az * inv); o.w = f2bf(aw * inv);
    *(ushort4*)(acat + fmoff(node, cbase + off, 512)) = o;
}

// ---------------- host ----------------

extern "C" void kernel_launch(void* const* d_in, const int* in_sizes, int n_in,
                              void* d_out, int out_size, void* d_ws, size_t ws_size,
                              hipStream_t stream) {
    (void)in_sizes; (void)n_in; (void)out_size; (void)ws_size;
    const float* x        = (const float*)d_in[0];
    const int*   ei       = (const int*)d_in[1];
    const int*   eei      = (const int*)d_in[2];
    const float* Wqkv_loc = (const float*)d_in[3];
    const float* bqkv_loc = (const float*)d_in[4];
    const float* Wo_loc   = (const float*)d_in[5];
    const float* bo_loc   = (const float*)d_in[6];
    const float* Wqkv_exp = (const float*)d_in[7];
    const float* bqkv_exp = (const float*)d_in[8];
    const float* Wo_exp   = (const float*)d_in[9];
    const float* bo_exp   = (const float*)d_in[10];
    const float* ln_g     = (const float*)d_in[11];
    const float* ln_b     = (const float*)d_in[12];
    const float* W1       = (const float*)d_in[13];
    const float* b1       = (const float*)d_in[14];
    const float* W2       = (const float*)d_in[15];
    const float* b2       = (const float*)d_in[16];

    char* wsp = (char*)d_ws;
    size_t off = 0;
    auto carve = [&](size_t bytes) -> void* {
        void* p = wsp + off;
        off += (bytes + 255) & ~(size_t)255;
        return p;
    };
    float* h_f    = (float*)carve((size_t)NNODES * 256 * 4);
    u16*   h_b    = (u16*)carve((size_t)MPAD * 256 * 2);      // FM
    u16*   qb_loc = (u16*)carve((size_t)NNODES * 256 * 2);    // dense q, 512B/row
    u16*   kv_loc = (u16*)carve((size_t)NNODES * 512 * 2);    // interleaved k|v, 1KB/row
    u16*   qb_exp = (u16*)carve((size_t)NNODES * 256 * 2);
    u16*   kv_exp = (u16*)carve((size_t)NNODES * 512 * 2);
    u16*   acat   = (u16*)carve((size_t)MPAD * 512 * 2);      // FM(M x 512): loc|exp attn out
    u16*   wbf    = (u16*)carve((size_t)3 * 1048576 * 2);     // FM weights
    float* bcat   = (float*)carve((size_t)3 * 1536 * 4);
    float* bsum   = (float*)carve((size_t)3 * 256 * 4);
    int*   cnt    = (int*)carve((size_t)NREAL * 4);
    int*   indptr = (int*)carve((size_t)(NREAL + 1) * 4);
    int*   fill   = (int*)carve((size_t)NREAL * 4);
    int*   srcs   = (int*)carve((size_t)E_EDGES * 4);
    int*   ecnt   = (int*)carve((size_t)NNODES * 4);
    int*   esrcs  = (int*)carve((size_t)NNODES * 4 * 4);
    float* part   = (float*)carve((size_t)NVNW * 264 * 4);

    hinit_kernel<<<(NNODES * 64 + 255) / 256, 256, 0, stream>>>(x, h_f, h_b);
    init_kernel<<<(NNODES + 255) / 256, 256, 0, stream>>>(
        cnt, fill, ecnt, bqkv_loc, bqkv_exp, bcat, bo_loc, bo_exp, bsum);
    csr_count_kernel<<<(E_EDGES + 255) / 256, 256, 0, stream>>>(ei, cnt);
    csr_scan_kernel<<<1, 256, 0, stream>>>(cnt, indptr);
    csr_scatter_kernel<<<(E_EDGES + 255) / 256, 256, 0, stream>>>(ei, indptr, fill, srcs);
    exp_scatter_kernel<<<(NEXP + 255) / 256, 256, 0, stream>>>(eei, ecnt, esrcs);
    wconv_all_kernel<<<(3 * 1048576 + 255) / 256, 256, 0, stream>>>(
        Wqkv_loc, Wqkv_exp, Wo_loc, Wo_exp, W1, W2, wbf);

    const int ATTN_BLOCKS = (NVNW + NREAL + NNODES + 3) / 4;   // 10081
    const int RW32_BLOCKS = MPAD / 32;                         // 628
    const int QKV_BLOCKS  = RW32_BLOCKS * 6;                   // 3768

    for (int l = 0; l < 3; l++) {
        const u16* wqkvC = wbf + (size_t)l * 1048576 + 0;
        const u16* wocat = wbf + (size_t)l * 1048576 + 393216;
        const u16* w1T   = wbf + (size_t)l * 1048576 + 524288;
        const u16* w2T   = wbf + (size_t)l * 1048576 + 786432;

        // fused qkv GEMM (loc|exp), 32-row rw, split-store q / k|v (pre-permuted)
        qkv_rw<<<QKV_BLOCKS, 256, 0, stream>>>(
            h_b, wqkvC, bcat + l * 1536,
            qb_loc, kv_loc, qb_exp, kv_exp, NNODES);

        // fused: vn online partials + local + expander edge attention -> acat/part
        attn_fused_kernel<<<ATTN_BLOCKS, 256, 0, stream>>>(
            qb_loc, kv_loc, qb_exp, kv_exp, indptr, srcs, esrcs, acat, part);

        // Wo-cat GEMM + residual + LayerNorm fused (+ inline vn merge in block VN/32):
        // h = LN(h_f + acat@[WoL;WoE] + bsum) -> h_f (f32) + h_b (FM bf16)
        wo_ln_rw<<<RW32_BLOCKS, 256, 0, stream>>>(
            acat, wocat, bsum + l * 256, h_f,
            ln_g + l * 256, ln_b + l * 256, h_f, h_b, part, acat, NNODES);

        // fused FFN: h += gelu(h@W1+b1)@W2 + b2 (mid staged per-chunk in LDS)
        if (l < 2) {
            ffn_fused<<<RW32_BLOCKS, 256, 0, stream>>>(
                h_b, w1T, w2T, b1 + l * 1024, b2 + l * 256,
                h_f, h_f, h_b, 0, NNODES);
        } else {
            ffn_fused<<<RW32_BLOCKS, 256, 0, stream>>>(
                h_b, w1T, w2T, b1 + l * 1024, b2 + l * 256,
                h_f, (float*)d_out, nullptr, 1, NNODES);
        }
    }
}

// Round 11
// 764.980 us; speedup vs baseline: 1.0900x; 1.0900x over previous
//
#include <hip/hip_runtime.h>
#include <stdint.h>

#define NREAL   20000
#define NNODES  20001
#define VN      20000
#define E_EDGES 320000
#define NEXP    80004
#define MPAD    20096   // rows padded to 157*128 for fragment-major buffers
#define NVNW    320     // vn online waves (fused into attn kernel)

typedef unsigned short u16;
typedef unsigned int   u32;
typedef __bf16 bf16x8 __attribute__((ext_vector_type(8)));
typedef float  f32x4  __attribute__((ext_vector_type(4)));
typedef u16    u16x8  __attribute__((ext_vector_type(8)));

// fragment-major layout: element (row, col) of an LD-wide matrix lives at
// (row/16)*(16*LD) + (col/8)*128 + (row%16)*8 + (col%8).
__device__ __host__ __forceinline__ size_t fmoff(int row, int col, int LD) {
    return (size_t)(row >> 4) * ((size_t)LD * 16) + (size_t)((col >> 3) * 128)
         + (size_t)((row & 15) * 8) + (size_t)(col & 7);
}

// qkv column permutation: within one graph's 768 cols [Q|K|V], K/V are
// interleaved at 4-col granularity so dest col 256+8j+r holds K[4j+r] (r<4)
// or V[4j+r-4] (r>=4).  Baked into weights+bias so the GEMM stores contiguously.
__device__ __forceinline__ int qkv_perm(int n) {  // n in [0,768) source -> dest
    if (n < 256) return n;
    int u = n - 256;
    int part = u >> 8;        // 0 = K, 1 = V
    int cl = u & 255;
    return 256 + (cl >> 2) * 8 + part * 4 + (cl & 3);
}

__device__ __forceinline__ float bf2f(u16 v) {
    union { u32 u; float f; } x; x.u = ((u32)v) << 16; return x.f;
}
__device__ __forceinline__ u16 f2bf(float f) {
    union { float f; u32 u; } x; x.f = f;
    u32 r = (x.u + 0x7fffu + ((x.u >> 16) & 1u)) >> 16;
    return (u16)r;
}
__device__ __forceinline__ float4 cvt4(ushort4 u) {
    return make_float4(bf2f(u.x), bf2f(u.y), bf2f(u.z), bf2f(u.w));
}
__device__ __forceinline__ float4 ld4bf(const u16* p) { return cvt4(*(const ushort4*)p); }
// interleaved kv row: per 8-u16 chunk = [k0 k1 k2 k3 | v0 v1 v2 v3]
__device__ __forceinline__ float4 cvtk8(u16x8 r) {
    return make_float4(bf2f(r[0]), bf2f(r[1]), bf2f(r[2]), bf2f(r[3]));
}
__device__ __forceinline__ float4 cvtv8(u16x8 r) {
    return make_float4(bf2f(r[4]), bf2f(r[5]), bf2f(r[6]), bf2f(r[7]));
}

// ---------------- setup kernels ----------------

__global__ void hinit_kernel(const float* __restrict__ x, float* __restrict__ h,
                             u16* __restrict__ hb) {
    int idx = blockIdx.x * 256 + threadIdx.x;
    if (idx >= NNODES * 64) return;
    int row = idx >> 6, c0 = (idx & 63) * 4;
    float4 v = make_float4(0.f, 0.f, 0.f, 0.f);
    if (row < NREAL) v = *(const float4*)(x + (size_t)row * 256 + c0);
    *(float4*)(h + (size_t)row * 256 + c0) = v;
    ushort4 o;
    o.x = f2bf(v.x); o.y = f2bf(v.y); o.z = f2bf(v.z); o.w = f2bf(v.w);
    *(ushort4*)(hb + fmoff(row, c0, 256)) = o;
}

__global__ void init_kernel(int* cnt, int* fill, int* ecnt,
                            const float* __restrict__ bl, const float* __restrict__ be,
                            float* __restrict__ bcat,
                            const float* __restrict__ bol, const float* __restrict__ boe,
                            float* __restrict__ bsum) {
    int i = blockIdx.x * 256 + threadIdx.x;
    if (i < NREAL) { cnt[i] = 0; fill[i] = 0; }
    if (i < NNODES) ecnt[i] = 0;
    if (i < 3 * 1536) {
        int l = i / 1536, c = i - l * 1536;   // source col
        float v = (c < 768) ? bl[l * 768 + c] : be[l * 768 + c - 768];
        int cc = (c >= 768) ? c - 768 : c;
        int d = qkv_perm(cc) + ((c >= 768) ? 768 : 0);
        bcat[l * 1536 + d] = v;
    }
    if (i < 3 * 256) bsum[i] = bol[i] + boe[i];
}

__global__ void csr_count_kernel(const int* __restrict__ ei, int* __restrict__ cnt) {
    int e = blockIdx.x * 256 + threadIdx.x;
    if (e < E_EDGES) atomicAdd(&cnt[ei[E_EDGES + e]], 1);
}

__global__ void csr_scan_kernel(const int* __restrict__ cnt, int* __restrict__ indptr) {
    __shared__ int ssum[256];
    int t = threadIdx.x;
    int c0 = t * 79;
    int s = 0;
    for (int j = 0; j < 79; j++) {
        int i = c0 + j;
        if (i < NREAL) s += cnt[i];
    }
    ssum[t] = s;
    __syncthreads();
    for (int d2 = 1; d2 < 256; d2 <<= 1) {
        int v = (t >= d2) ? ssum[t - d2] : 0;
        __syncthreads();
        ssum[t] += v;
        __syncthreads();
    }
    int run = (t == 0) ? 0 : ssum[t - 1];
    for (int j = 0; j < 79; j++) {
        int i = c0 + j;
        if (i < NREAL) { indptr[i] = run; run += cnt[i]; }
    }
    if (t == 255) indptr[NREAL] = run;
}

__global__ void csr_scatter_kernel(const int* __restrict__ ei, const int* __restrict__ indptr,
                                   int* __restrict__ fill, int* __restrict__ srcs) {
    int e = blockIdx.x * 256 + threadIdx.x;
    if (e < E_EDGES) {
        int d = ei[E_EDGES + e];
        int pos = indptr[d] + atomicAdd(&fill[d], 1);
        srcs[pos] = ei[e];
    }
}

__global__ void exp_scatter_kernel(const int* __restrict__ eei, int* __restrict__ ecnt,
                                   int* __restrict__ esrcs) {
    int e = blockIdx.x * 256 + threadIdx.x;
    if (e < NEXP) {
        int d = eei[NEXP + e];
        int pos = atomicAdd(&ecnt[d], 1);
        esrcs[d * 4 + pos] = eei[e];
    }
}

// ALL weights -> bf16 fragment-major, one launch. Per-layer slab 1048576 u16:
// [0] WqkvL(FM 768x256, cols k/v-interleave-permuted) [196608] WqkvE (same perm)
// [393216] Wo-cat FM(256 x 512) (K-stacked WoL;WoE)
// [524288] W1 FM(1024x256) [786432] W2 FM(256x1024)
__global__ void wconv_all_kernel(const float* __restrict__ WqkvL, const float* __restrict__ WqkvE,
                                 const float* __restrict__ WoL, const float* __restrict__ WoE,
                                 const float* __restrict__ W1, const float* __restrict__ W2,
                                 u16* __restrict__ out) {
    int i = blockIdx.x * 256 + threadIdx.x;
    if (i >= 3 * 1048576) return;
    int l = i / 1048576, r = i - l * 1048576;
    if (r >= 393216 && r < 524288) {
        // Wo-cat: r2 = k*256 + n, k in [0,512), n in [0,256)
        int r2 = r - 393216;
        int k = r2 >> 8, n = r2 & 255;
        float v = (k < 256) ? WoL[(size_t)l * 65536 + k * 256 + n]
                            : WoE[(size_t)l * 65536 + (k - 256) * 256 + n];
        out[(size_t)l * 1048576 + 393216 + fmoff(n, k, 512)] = f2bf(v);
        return;
    }
    const float* src; int K, N; int base;
    if (r < 196608)      { src = WqkvL; K = 256;  N = 768;  base = 0; }
    else if (r < 393216) { src = WqkvE; K = 256;  N = 768;  base = 196608; }
    else if (r < 786432) { src = W1;    K = 256;  N = 1024; base = 524288; }
    else                 { src = W2;    K = 1024; N = 256;  base = 786432; }
    int r2 = r - base;
    int k = r2 / N, n = r2 - k * N;
    int d = (r < 393216) ? qkv_perm(n) : n;   // bake kv interleave into qkv weights
    out[(size_t)l * 1048576 + base + fmoff(d, k, K)] = f2bf(src[(size_t)l * K * N + r2]);
}

// ---------------- qkv GEMM (K=256): 32x256 block, 4 waves, depth-3 prefetch ----
// wave w: 32 rows x 64 cols (2x4 frags); 3768 blocks (~15 waves/CU in flight).
// Same ascending-K accumulation order as before -> bitwise-identical outputs.
__global__ __launch_bounds__(256) void qkv_rw(
    const u16* __restrict__ A, const u16* __restrict__ Bt, const float* __restrict__ bias,
    u16* __restrict__ Q0, u16* __restrict__ KV0,
    u16* __restrict__ Q1, u16* __restrict__ KV1, int M) {
    const int lin = blockIdx.x;
    const int mt = lin / 6, ns = lin - mt * 6;
    const int tm = mt * 32;
    if (tm >= M) return;
    const int tid = threadIdx.x;
    const int w = tid >> 6, lane = tid & 63;
    const int lm = lane & 15, q = lane >> 4;

    f32x4 acc[2][4];
#pragma unroll
    for (int a = 0; a < 2; a++)
#pragma unroll
        for (int b = 0; b < 4; b++) acc[a][b] = (f32x4)0.0f;

    const u16* apf[2];
    const u16* bpf[4];
#pragma unroll
    for (int mi = 0; mi < 2; mi++)
        apf[mi] = A + (size_t)(tm / 16 + mi) * 4096 + q * 128 + lm * 8;
#pragma unroll
    for (int ni = 0; ni < 4; ni++)
        bpf[ni] = Bt + (size_t)(ns * 16 + w * 4 + ni) * 4096 + q * 128 + lm * 8;

    bf16x8 sA[4][2], sB[4][4];
#pragma unroll
    for (int s = 0; s < 3; s++) {
#pragma unroll
        for (int mi = 0; mi < 2; mi++) sA[s][mi] = *(const bf16x8*)(apf[mi] + s * 512);
#pragma unroll
        for (int ni = 0; ni < 4; ni++) sB[s][ni] = *(const bf16x8*)(bpf[ni] + s * 512);
    }
#pragma unroll
    for (int i = 0; i < 8; i++) {
        const int cu = i & 3, pf = (i + 3) & 3;
        if (i + 3 < 8) {
#pragma unroll
            for (int mi = 0; mi < 2; mi++) sA[pf][mi] = *(const bf16x8*)(apf[mi] + (i + 3) * 512);
#pragma unroll
            for (int ni = 0; ni < 4; ni++) sB[pf][ni] = *(const bf16x8*)(bpf[ni] + (i + 3) * 512);
        }
#pragma unroll
        for (int mi = 0; mi < 2; mi++)
#pragma unroll
            for (int ni = 0; ni < 4; ni++)
                acc[mi][ni] = __builtin_amdgcn_mfma_f32_16x16x32_bf16(
                    sB[cu][ni], sA[cu][mi], acc[mi][ni], 0, 0, 0);
    }

    float4 b4[4];
#pragma unroll
    for (int ni = 0; ni < 4; ni++)
        b4[ni] = *(const float4*)(bias + ns * 256 + w * 64 + ni * 16 + q * 4);

#pragma unroll
    for (int mi = 0; mi < 2; mi++) {
        int grow = tm + mi * 16 + lm;
        if (grow >= M) continue;
#pragma unroll
        for (int ni = 0; ni < 4; ni++) {
            int gcol = ns * 256 + w * 64 + ni * 16 + q * 4;
            float v0 = acc[mi][ni][0] + b4[ni].x;
            float v1 = acc[mi][ni][1] + b4[ni].y;
            float v2 = acc[mi][ni][2] + b4[ni].z;
            float v3 = acc[mi][ni][3] + b4[ni].w;
            ushort4 o;
            o.x = f2bf(v0); o.y = f2bf(v1); o.z = f2bf(v2); o.w = f2bf(v3);
            u16* dst;
            if (gcol < 256)       dst = Q0  + (size_t)grow * 256 + gcol;
            else if (gcol < 768)  dst = KV0 + (size_t)grow * 512 + (gcol - 256);
            else if (gcol < 1024) dst = Q1  + (size_t)grow * 256 + (gcol - 768);
            else                  dst = KV1 + (size_t)grow * 512 + (gcol - 1024);
            *(ushort4*)dst = o;
        }
    }
}

// ---------------- FFN-W1 GEMM (K=256): 32x256 block, depth-3 prefetch ----------
// 2512 blocks; gelu epilogue -> mid FM(LD 1024).
__global__ __launch_bounds__(256) void ffn1_rw(
    const u16* __restrict__ A, const u16* __restrict__ Bt, const float* __restrict__ bias,
    u16* __restrict__ Cb, int M) {
    const int lin = blockIdx.x;
    const int mt = lin >> 2, ns = lin & 3;
    const int tm = mt * 32;
    if (tm >= M) return;
    const int tid = threadIdx.x;
    const int w = tid >> 6, lane = tid & 63;
    const int lm = lane & 15, q = lane >> 4;

    f32x4 acc[2][4];
#pragma unroll
    for (int a = 0; a < 2; a++)
#pragma unroll
        for (int b = 0; b < 4; b++) acc[a][b] = (f32x4)0.0f;

    const u16* apf[2];
    const u16* bpf[4];
#pragma unroll
    for (int mi = 0; mi < 2; mi++)
        apf[mi] = A + (size_t)(tm / 16 + mi) * 4096 + q * 128 + lm * 8;
#pragma unroll
    for (int ni = 0; ni < 4; ni++)
        bpf[ni] = Bt + (size_t)(ns * 16 + w * 4 + ni) * 4096 + q * 128 + lm * 8;

    bf16x8 sA[4][2], sB[4][4];
#pragma unroll
    for (int s = 0; s < 3; s++) {
#pragma unroll
        for (int mi = 0; mi < 2; mi++) sA[s][mi] = *(const bf16x8*)(apf[mi] + s * 512);
#pragma unroll
        for (int ni = 0; ni < 4; ni++) sB[s][ni] = *(const bf16x8*)(bpf[ni] + s * 512);
    }
#pragma unroll
    for (int i = 0; i < 8; i++) {
        const int cu = i & 3, pf = (i + 3) & 3;
        if (i + 3 < 8) {
#pragma unroll
            for (int mi = 0; mi < 2; mi++) sA[pf][mi] = *(const bf16x8*)(apf[mi] + (i + 3) * 512);
#pragma unroll
            for (int ni = 0; ni < 4; ni++) sB[pf][ni] = *(const bf16x8*)(bpf[ni] + (i + 3) * 512);
        }
#pragma unroll
        for (int mi = 0; mi < 2; mi++)
#pragma unroll
            for (int ni = 0; ni < 4; ni++)
                acc[mi][ni] = __builtin_amdgcn_mfma_f32_16x16x32_bf16(
                    sB[cu][ni], sA[cu][mi], acc[mi][ni], 0, 0, 0);
    }

    float4 b4[4];
#pragma unroll
    for (int ni = 0; ni < 4; ni++)
        b4[ni] = *(const float4*)(bias + ns * 256 + w * 64 + ni * 16 + q * 4);

#pragma unroll
    for (int mi = 0; mi < 2; mi++) {
        int grow = tm + mi * 16 + lm;
        if (grow >= M) continue;
#pragma unroll
        for (int ni = 0; ni < 4; ni++) {
            int gcol = ns * 256 + w * 64 + ni * 16 + q * 4;
            float v0 = acc[mi][ni][0] + b4[ni].x;
            float v1 = acc[mi][ni][1] + b4[ni].y;
            float v2 = acc[mi][ni][2] + b4[ni].z;
            float v3 = acc[mi][ni][3] + b4[ni].w;
            float g0, g1, g2, g3;
            {
                float u = 0.7978845608f * (v0 + 0.044715f * v0 * v0 * v0);
                g0 = 0.5f * v0 * (2.0f - 2.0f / (__expf(2.0f * u) + 1.0f));
            }
            {
                float u = 0.7978845608f * (v1 + 0.044715f * v1 * v1 * v1);
                g1 = 0.5f * v1 * (2.0f - 2.0f / (__expf(2.0f * u) + 1.0f));
            }
            {
                float u = 0.7978845608f * (v2 + 0.044715f * v2 * v2 * v2);
                g2 = 0.5f * v2 * (2.0f - 2.0f / (__expf(2.0f * u) + 1.0f));
            }
            {
                float u = 0.7978845608f * (v3 + 0.044715f * v3 * v3 * v3);
                g3 = 0.5f * v3 * (2.0f - 2.0f / (__expf(2.0f * u) + 1.0f));
            }
            ushort4 o;
            o.x = f2bf(g0); o.y = f2bf(g1); o.z = f2bf(g2); o.w = f2bf(g3);
            *(ushort4*)(Cb + fmoff(grow, gcol, 1024)) = o;
        }
    }
}

// ---------------- Wo GEMM + residual + LayerNorm (K=512), depth-3 prefetch ------
// 32 rows x 256 cols per block, 4 waves; 628 blocks.  Block VN/32 first performs
// the vn partial merge (was vn_merge_kernel) -- barriers order the acat write
// before this block's own A-loads; no other block reads row VN.
__global__ __launch_bounds__(256) void wo_ln_rw(
    const u16* A, const u16* __restrict__ Bt, const float* __restrict__ bias,
    const float* __restrict__ resid, const float* __restrict__ g,
    const float* __restrict__ bvec, float* __restrict__ hout, u16* __restrict__ hb,
    const float* __restrict__ part, u16* acat_w, int M) {
    __shared__ float smS[32][4];
    __shared__ float smQ[32][4];
    const int tm = blockIdx.x * 32;
    if (tm >= M) return;
    const int tid = threadIdx.x;
    const int w = tid >> 6, lane = tid & 63;
    const int lm = lane & 15, q = lane >> 4;

    if (blockIdx.x == VN / 32) {
        // vn partial merge: 4 waves x 80 partials + cross-wave LDS combine
        __shared__ float smm[4][64][6];
        int hh = lane >> 4;
        int ov = (hh << 6) + (lane & 15) * 4;
        float mm = -1e30f, ll = 0.0f;
        float ax = 0, ay = 0, az = 0, aw = 0;
        for (int p = w * 80; p < w * 80 + 80; p++) {
            const float* pp = part + (size_t)p * 264;
            float pm = pp[hh], pl = pp[4 + hh];
            float4 nm = *(const float4*)(pp + 8 + ov);
            float Mn = fmaxf(mm, pm);
            float s0 = __expf(mm - Mn);
            float s1 = __expf(pm - Mn);
            ax = ax * s0 + nm.x * s1;
            ay = ay * s0 + nm.y * s1;
            az = az * s0 + nm.z * s1;
            aw = aw * s0 + nm.w * s1;
            ll = ll * s0 + pl * s1;
            mm = Mn;
        }
        smm[w][lane][0] = mm; smm[w][lane][1] = ll;
        smm[w][lane][2] = ax; smm[w][lane][3] = ay;
        smm[w][lane][4] = az; smm[w][lane][5] = aw;
        __syncthreads();
        if (w == 0) {
            float M2 = -1e30f, L2 = 0.0f;
            float bx = 0, by = 0, bz = 0, bw = 0;
#pragma unroll
            for (int p = 0; p < 4; p++) {
                float pm = smm[p][lane][0], pl = smm[p][lane][1];
                float Mn = fmaxf(M2, pm);
                float s0 = __expf(M2 - Mn);
                float s1 = __expf(pm - Mn);
                bx = bx * s0 + smm[p][lane][2] * s1;
                by = by * s0 + smm[p][lane][3] * s1;
                bz = bz * s0 + smm[p][lane][4] * s1;
                bw = bw * s0 + smm[p][lane][5] * s1;
                L2 = L2 * s0 + pl * s1;
                M2 = Mn;
            }
            float inv = 1.0f / (L2 + 1e-16f);
            ushort4 o;
            o.x = f2bf(bx * inv); o.y = f2bf(by * inv);
            o.z = f2bf(bz * inv); o.w = f2bf(bw * inv);
            *(ushort4*)(acat_w + fmoff(VN, ov, 512)) = o;
        }
        __syncthreads();
    }

    f32x4 acc[2][4];
#pragma unroll
    for (int a = 0; a < 2; a++)
#pragma unroll
        for (int b = 0; b < 4; b++) acc[a][b] = (f32x4)0.0f;

    const u16* apf[2];
    const u16* bpf[4];
#pragma unroll
    for (int mi = 0; mi < 2; mi++)
        apf[mi] = A + (size_t)(tm / 16 + mi) * 8192 + q * 128 + lm * 8;
#pragma unroll
    for (int ni = 0; ni < 4; ni++)
        bpf[ni] = Bt + (size_t)(w * 4 + ni) * 8192 + q * 128 + lm * 8;

    bf16x8 sA[4][2], sB[4][4];
#pragma unroll
    for (int s = 0; s < 3; s++) {
#pragma unroll
        for (int mi = 0; mi < 2; mi++) sA[s][mi] = *(const bf16x8*)(apf[mi] + s * 512);
#pragma unroll
        for (int ni = 0; ni < 4; ni++) sB[s][ni] = *(const bf16x8*)(bpf[ni] + s * 512);
    }
#pragma unroll
    for (int i = 0; i < 16; i++) {
        const int cu = i & 3, pf = (i + 3) & 3;
        if (i + 3 < 16) {
#pragma unroll
            for (int mi = 0; mi < 2; mi++) sA[pf][mi] = *(const bf16x8*)(apf[mi] + (i + 3) * 512);
#pragma unroll
            for (int ni = 0; ni < 4; ni++) sB[pf][ni] = *(const bf16x8*)(bpf[ni] + (i + 3) * 512);
        }
#pragma unroll
        for (int mi = 0; mi < 2; mi++)
#pragma unroll
            for (int ni = 0; ni < 4; ni++)
                acc[mi][ni] = __builtin_amdgcn_mfma_f32_16x16x32_bf16(
                    sB[cu][ni], sA[cu][mi], acc[mi][ni], 0, 0, 0);
    }

    // v = resid + (acc + bias)
    float4 b4[4];
#pragma unroll
    for (int ni = 0; ni < 4; ni++)
        b4[ni] = *(const float4*)(bias + w * 64 + ni * 16 + q * 4);
#pragma unroll
    for (int mi = 0; mi < 2; mi++) {
        int grow = tm + mi * 16 + lm;
#pragma unroll
        for (int ni = 0; ni < 4; ni++) {
            int gcol = w * 64 + ni * 16 + q * 4;
            size_t idx = (size_t)grow * 256 + gcol;
            float4 rv = *(const float4*)(resid + idx);  // OOB rows read scratch (safe)
            acc[mi][ni][0] = rv.x + (acc[mi][ni][0] + b4[ni].x);
            acc[mi][ni][1] = rv.y + (acc[mi][ni][1] + b4[ni].y);
            acc[mi][ni][2] = rv.z + (acc[mi][ni][2] + b4[ni].z);
            acc[mi][ni][3] = rv.w + (acc[mi][ni][3] + b4[ni].w);
        }
    }

    // LayerNorm over each row's 256 cols (4 waves x 64 cols, LDS cross-wave)
    float s1[2];
#pragma unroll
    for (int mi = 0; mi < 2; mi++) {
        float s = 0.f;
#pragma unroll
        for (int ni = 0; ni < 4; ni++)
            s += acc[mi][ni][0] + acc[mi][ni][1] + acc[mi][ni][2] + acc[mi][ni][3];
        s += __shfl_xor(s, 16); s += __shfl_xor(s, 32);
        s1[mi] = s;
    }
    if (lane < 16) {
        smS[lm][w] = s1[0];
        smS[16 + lm][w] = s1[1];
    }
    __syncthreads();
    float mu[2];
#pragma unroll
    for (int mi = 0; mi < 2; mi++) {
        int r = mi * 16 + lm;
        mu[mi] = (smS[r][0] + smS[r][1] + smS[r][2] + smS[r][3]) * (1.0f / 256.0f);
    }
    float s2[2];
#pragma unroll
    for (int mi = 0; mi < 2; mi++) {
        float s = 0.f;
#pragma unroll
        for (int ni = 0; ni < 4; ni++) {
            float d0 = acc[mi][ni][0] - mu[mi];
            float d1 = acc[mi][ni][1] - mu[mi];
            float d2 = acc[mi][ni][2] - mu[mi];
            float d3 = acc[mi][ni][3] - mu[mi];
            s += d0 * d0 + d1 * d1 + d2 * d2 + d3 * d3;
        }
        s += __shfl_xor(s, 16); s += __shfl_xor(s, 32);
        s2[mi] = s;
    }
    if (lane < 16) {
        smQ[lm][w] = s2[0];
        smQ[16 + lm][w] = s2[1];
    }
    __syncthreads();
    float rinv[2];
#pragma unroll
    for (int mi = 0; mi < 2; mi++) {
        int r = mi * 16 + lm;
        float var = (smQ[r][0] + smQ[r][1] + smQ[r][2] + smQ[r][3]) * (1.0f / 256.0f);
        rinv[mi] = 1.0f / sqrtf(var + 1e-5f);
    }
#pragma unroll
    for (int mi = 0; mi < 2; mi++) {
        int grow = tm + mi * 16 + lm;
        if (grow >= M) continue;
#pragma unroll
        for (int ni = 0; ni < 4; ni++) {
            int gcol = w * 64 + ni * 16 + q * 4;
            float4 gv = *(const float4*)(g + gcol);
            float4 bv = *(const float4*)(bvec + gcol);
            float4 y;
            y.x = (acc[mi][ni][0] - mu[mi]) * rinv[mi] * gv.x + bv.x;
            y.y = (acc[mi][ni][1] - mu[mi]) * rinv[mi] * gv.y + bv.y;
            y.z = (acc[mi][ni][2] - mu[mi]) * rinv[mi] * gv.z + bv.z;
            y.w = (acc[mi][ni][3] - mu[mi]) * rinv[mi] * gv.w + bv.w;
            *(float4*)(hout + (size_t)grow * 256 + gcol) = y;
            ushort4 o;
            o.x = f2bf(y.x); o.y = f2bf(y.y); o.z = f2bf(y.z); o.w = f2bf(y.w);
            *(ushort4*)(hb + fmoff(grow, gcol, 256)) = o;
        }
    }
}

// ---------------- W2 GEMM + residual (K=1024), depth-3 prefetch -----------------
// 32 rows x 256 cols per block, 4 waves; 628 blocks; A read once.
// last=0: Cf(f32)=resid+v and Cb(FM bf16);  last=1: Cf only, rows < NREAL.
__global__ __launch_bounds__(256) void w2_rw(
    const u16* __restrict__ A, const u16* __restrict__ Bt, const float* __restrict__ bias,
    const float* __restrict__ resid, float* __restrict__ Cf, u16* __restrict__ Cb,
    int last, int M) {
    const int tm = blockIdx.x * 32;
    if (tm >= M) return;
    const int tid = threadIdx.x;
    const int w = tid >> 6, lane = tid & 63;
    const int lm = lane & 15, q = lane >> 4;

    f32x4 acc[2][4];
#pragma unroll
    for (int a = 0; a < 2; a++)
#pragma unroll
        for (int b = 0; b < 4; b++) acc[a][b] = (f32x4)0.0f;

    const u16* apf[2];
    const u16* bpf[4];
#pragma unroll
    for (int mi = 0; mi < 2; mi++)
        apf[mi] = A + (size_t)(tm / 16 + mi) * 16384 + q * 128 + lm * 8;
#pragma unroll
    for (int ni = 0; ni < 4; ni++)
        bpf[ni] = Bt + (size_t)(w * 4 + ni) * 16384 + q * 128 + lm * 8;

    bf16x8 sA[4][2], sB[4][4];
#pragma unroll
    for (int s = 0; s < 3; s++) {
#pragma unroll
        for (int mi = 0; mi < 2; mi++) sA[s][mi] = *(const bf16x8*)(apf[mi] + s * 512);
#pragma unroll
        for (int ni = 0; ni < 4; ni++) sB[s][ni] = *(const bf16x8*)(bpf[ni] + s * 512);
    }
#pragma unroll
    for (int i = 0; i < 32; i++) {
        const int cu = i & 3, pf = (i + 3) & 3;
        if (i + 3 < 32) {
#pragma unroll
            for (int mi = 0; mi < 2; mi++) sA[pf][mi] = *(const bf16x8*)(apf[mi] + (i + 3) * 512);
#pragma unroll
            for (int ni = 0; ni < 4; ni++) sB[pf][ni] = *(const bf16x8*)(bpf[ni] + (i + 3) * 512);
        }
#pragma unroll
        for (int mi = 0; mi < 2; mi++)
#pragma unroll
            for (int ni = 0; ni < 4; ni++)
                acc[mi][ni] = __builtin_amdgcn_mfma_f32_16x16x32_bf16(
                    sB[cu][ni], sA[cu][mi], acc[mi][ni], 0, 0, 0);
    }

    float4 b4[4];
#pragma unroll
    for (int ni = 0; ni < 4; ni++)
        b4[ni] = *(const float4*)(bias + w * 64 + ni * 16 + q * 4);

#pragma unroll
    for (int mi = 0; mi < 2; mi++) {
        int grow = tm + mi * 16 + lm;
        if (grow >= (last ? NREAL : M)) continue;
#pragma unroll
        for (int ni = 0; ni < 4; ni++) {
            int gcol = w * 64 + ni * 16 + q * 4;
            float v0 = acc[mi][ni][0] + b4[ni].x;
            float v1 = acc[mi][ni][1] + b4[ni].y;
            float v2 = acc[mi][ni][2] + b4[ni].z;
            float v3 = acc[mi][ni][3] + b4[ni].w;
            size_t idx = (size_t)grow * 256 + gcol;
            float4 rv = *(const float4*)(resid + idx);
            float o0 = rv.x + v0, o1 = rv.y + v1, o2 = rv.z + v2, o3 = rv.w + v3;
            *(float4*)(Cf + idx) = make_float4(o0, o1, o2, o3);
            if (!last) {
                ushort4 o;
                o.x = f2bf(o0); o.y = f2bf(o1); o.z = f2bf(o2); o.w = f2bf(o3);
                *(ushort4*)(Cb + fmoff(grow, gcol, 256)) = o;
            }
        }
    }
}

// ---------------- fused attention (vn partials + local + expander) ---------------
// kv rows are interleaved: chunk j (16B) = [k[4j..4j+3] | v[4j..4j+3]] -> one
// dwordx4 per lane per edge.  gw layout: [0,NVNW) vn partial waves,
// [NVNW, NVNW+NREAL) local nodes, [.., +NNODES) expander nodes.
__global__ void attn_fused_kernel(const u16* __restrict__ qb_loc, const u16* __restrict__ kv_loc,
                                  const u16* __restrict__ qb_exp, const u16* __restrict__ kv_exp,
                                  const int* __restrict__ indptr, const int* __restrict__ srcs,
                                  const int* __restrict__ esrcs,
                                  u16* __restrict__ acat, float* __restrict__ part) {
    int gw0 = (int)((blockIdx.x * (size_t)blockDim.x + threadIdx.x) >> 6);
    int gw = __builtin_amdgcn_readfirstlane(gw0);   // wave-uniform -> SGPR control flow
    int lane = threadIdx.x & 63;
    int h = lane >> 4;
    int off = (h << 6) + (lane & 15) * 4;   // u16 col in a 256-wide q row
    int coff = (off >> 2) * 8;              // u16 offset of interleaved 16B chunk

    if (gw < NVNW) {
        // vn dense attention: single-pass online partial
        int wv = gw;
        float4 qv = ld4bf(qb_loc + (size_t)VN * 256 + off);
        float m = -1e30f, l = 0.0f;
        float ax = 0, ay = 0, az = 0, aw = 0;
        for (int i = wv; i < NREAL; i += NVNW) {
            u16x8 r = *(const u16x8*)(kv_loc + (size_t)i * 512 + coff);
            float4 k4 = cvtk8(r);
            float4 v4 = cvtv8(r);
            float s = qv.x * k4.x + qv.y * k4.y + qv.z * k4.z + qv.w * k4.w;
            s += __shfl_xor(s, 1); s += __shfl_xor(s, 2);
            s += __shfl_xor(s, 4); s += __shfl_xor(s, 8);
            float sc = s * 0.125f;
            float mn = fmaxf(m, sc);
            float fold = __expf(m - mn);
            float ee = __expf(sc - mn);
            ax = ax * fold + v4.x * ee;
            ay = ay * fold + v4.y * ee;
            az = az * fold + v4.z * ee;
            aw = aw * fold + v4.w * ee;
            l = l * fold + ee;
            m = mn;
        }
        float* pp = part + (size_t)wv * 264;
        if ((lane & 15) == 0) { pp[h] = m; pp[4 + h] = l; }
        *(float4*)(pp + 8 + off) = make_float4(ax, ay, az, aw);
        return;
    }
    gw -= NVNW;

    const u16 *qb, *kv;
    const int* sl;
    int node, beg, deg, tot, cbase;
    if (gw < NREAL) {
        node = gw; qb = qb_loc; kv = kv_loc; sl = srcs; cbase = 0;
        beg = indptr[node]; deg = indptr[node + 1] - beg; tot = deg + 1;  // +vn edge
    } else if (gw < NREAL + NNODES) {
        node = gw - NREAL;
        qb = qb_exp; kv = kv_exp; sl = esrcs; cbase = 256;
        beg = node * 4; deg = 4; tot = 4;
    } else {
        return;
    }

    float4 qv = ld4bf(qb + (size_t)node * 256 + off);
    float m = -1e30f, l = 0.0f;
    float ax = 0, ay = 0, az = 0, aw = 0;

    if (tot <= 4) {
        u16x8 raw[4];
#pragma unroll
        for (int j = 0; j < 4; j++) {
            int s = (j < deg) ? sl[beg + j] : VN;
            raw[j] = *(const u16x8*)(kv + (size_t)s * 512 + coff);
        }
        float sc[4];
#pragma unroll
        for (int j = 0; j < 4; j++) {
            float4 k4 = cvtk8(raw[j]);
            float p = qv.x * k4.x + qv.y * k4.y + qv.z * k4.z + qv.w * k4.w;
            p += __shfl_xor(p, 1); p += __shfl_xor(p, 2);
            p += __shfl_xor(p, 4); p += __shfl_xor(p, 8);
            sc[j] = (j < tot) ? p * 0.125f : -1e30f;
        }
        float mn = fmaxf(fmaxf(sc[0], sc[1]), fmaxf(sc[2], sc[3]));
#pragma unroll
        for (int j = 0; j < 4; j++) {
            float ee = __expf(sc[j] - mn);
            float4 v4 = cvtv8(raw[j]);
            ax += v4.x * ee; ay += v4.y * ee; az += v4.z * ee; aw += v4.w * ee;
            l += ee;
        }
        m = mn;
    } else {
        // double-buffered 8-edge chunks: prefetch chunk c+1 while processing c
        const int nch = (tot + 7) >> 3;
        u16x8 rA[8], rB[8];
#pragma unroll
        for (int j = 0; j < 8; j++) {
            int s = (j < deg) ? sl[beg + j] : VN;
            rA[j] = *(const u16x8*)(kv + (size_t)s * 512 + coff);
        }
        for (int c = 0; c < nch; c++) {
            if (c + 1 < nch) {
                const int e0n = (c + 1) * 8;
#pragma unroll
                for (int j = 0; j < 8; j++) {
                    int e = e0n + j;
                    int s = (e < deg) ? sl[beg + e] : VN;
                    rB[j] = *(const u16x8*)(kv + (size_t)s * 512 + coff);
                }
            }
            const int e0 = c * 8;
            float sc[8];
#pragma unroll
            for (int j = 0; j < 8; j++) {
                float4 k4 = cvtk8(rA[j]);
                float p = qv.x * k4.x + qv.y * k4.y + qv.z * k4.z + qv.w * k4.w;
                p += __shfl_xor(p, 1); p += __shfl_xor(p, 2);
                p += __shfl_xor(p, 4); p += __shfl_xor(p, 8);
                sc[j] = (e0 + j < tot) ? p * 0.125f : -1e30f;
            }
            float cmax = fmaxf(fmaxf(fmaxf(sc[0], sc[1]), fmaxf(sc[2], sc[3])),
                               fmaxf(fmaxf(sc[4], sc[5]), fmaxf(sc[6], sc[7])));
            float mn = fmaxf(m, cmax);
            float fold = __expf(m - mn);
            ax *= fold; ay *= fold; az *= fold; aw *= fold; l *= fold;
#pragma unroll
            for (int j = 0; j < 8; j++) {
                float ee = __expf(sc[j] - mn);
                float4 v4 = cvtv8(rA[j]);
                ax += v4.x * ee; ay += v4.y * ee; az += v4.z * ee; aw += v4.w * ee;
                l += ee;
            }
            m = mn;
#pragma unroll
            for (int j = 0; j < 8; j++) rA[j] = rB[j];
        }
    }
    float inv = 1.0f / (l + 1e-16f);
    ushort4 o;
    o.x = f2bf(ax * inv); o.y = f2bf(ay * inv);
    o.z = f2bf(az * inv); o.w = f2bf(aw * inv);
    *(ushort4*)(acat + fmoff(node, cbase + off, 512)) = o;
}

// ---------------- host ----------------

extern "C" void kernel_launch(void* const* d_in, const int* in_sizes, int n_in,
                              void* d_out, int out_size, void* d_ws, size_t ws_size,
                              hipStream_t stream) {
    (void)in_sizes; (void)n_in; (void)out_size;
    const float* x        = (const float*)d_in[0];
    const int*   ei       = (const int*)d_in[1];
    const int*   eei      = (const int*)d_in[2];
    const float* Wqkv_loc = (const float*)d_in[3];
    const float* bqkv_loc = (const float*)d_in[4];
    const float* Wo_loc   = (const float*)d_in[5];
    const float* bo_loc   = (const float*)d_in[6];
    const float* Wqkv_exp = (const float*)d_in[7];
    const float* bqkv_exp = (const float*)d_in[8];
    const float* Wo_exp   = (const float*)d_in[9];
    const float* bo_exp   = (const float*)d_in[10];
    const float* ln_g     = (const float*)d_in[11];
    const float* ln_b     = (const float*)d_in[12];
    const float* W1       = (const float*)d_in[13];
    const float* b1       = (const float*)d_in[14];
    const float* W2       = (const float*)d_in[15];
    const float* b2       = (const float*)d_in[16];

    char* wsp = (char*)d_ws;
    size_t off = 0;
    auto carve = [&](size_t bytes) -> void* {
        void* p = wsp + off;
        off += (bytes + 255) & ~(size_t)255;
        return p;
    };
    float* h_f    = (float*)carve((size_t)NNODES * 256 * 4);
    u16*   h_b    = (u16*)carve((size_t)MPAD * 256 * 2);      // FM
    u16*   qb_loc = (u16*)carve((size_t)NNODES * 256 * 2);    // dense q, 512B/row
    u16*   kv_loc = (u16*)carve((size_t)NNODES * 512 * 2);    // interleaved k|v, 1KB/row
    u16*   qb_exp = (u16*)carve((size_t)NNODES * 256 * 2);
    u16*   kv_exp = (u16*)carve((size_t)NNODES * 512 * 2);
    u16*   acat   = (u16*)carve((size_t)MPAD * 512 * 2);      // FM(M x 512): loc|exp attn out
    u16*   wbf    = (u16*)carve((size_t)3 * 1048576 * 2);     // FM weights
    float* bcat   = (float*)carve((size_t)3 * 1536 * 4);
    float* bsum   = (float*)carve((size_t)3 * 256 * 4);
    int*   cnt    = (int*)carve((size_t)NREAL * 4);
    int*   indptr = (int*)carve((size_t)(NREAL + 1) * 4);
    int*   fill   = (int*)carve((size_t)NREAL * 4);
    int*   srcs   = (int*)carve((size_t)E_EDGES * 4);
    int*   ecnt   = (int*)carve((size_t)NNODES * 4);
    int*   esrcs  = (int*)carve((size_t)NNODES * 4 * 4);
    float* part   = (float*)carve((size_t)NVNW * 264 * 4);
    // dedicated FFN mid buffer FM(MPAD x 1024); fall back to the qb_loc alias
    // if the workspace is too small.
    u16*   mid_d  = (u16*)carve((size_t)MPAD * 1024 * 2);
    u16*   mid    = (ws_size >= off) ? mid_d : qb_loc;

    hinit_kernel<<<(NNODES * 64 + 255) / 256, 256, 0, stream>>>(x, h_f, h_b);
    init_kernel<<<(NNODES + 255) / 256, 256, 0, stream>>>(
        cnt, fill, ecnt, bqkv_loc, bqkv_exp, bcat, bo_loc, bo_exp, bsum);
    csr_count_kernel<<<(E_EDGES + 255) / 256, 256, 0, stream>>>(ei, cnt);
    csr_scan_kernel<<<1, 256, 0, stream>>>(cnt, indptr);
    csr_scatter_kernel<<<(E_EDGES + 255) / 256, 256, 0, stream>>>(ei, indptr, fill, srcs);
    exp_scatter_kernel<<<(NEXP + 255) / 256, 256, 0, stream>>>(eei, ecnt, esrcs);
    wconv_all_kernel<<<(3 * 1048576 + 255) / 256, 256, 0, stream>>>(
        Wqkv_loc, Wqkv_exp, Wo_loc, Wo_exp, W1, W2, wbf);

    const int ATTN_BLOCKS = (NVNW + NREAL + NNODES + 3) / 4;   // 10081
    const int RW32_BLOCKS = MPAD / 32;                         // 628
    const int QKV_BLOCKS  = RW32_BLOCKS * 6;                   // 3768
    const int FFN1_BLOCKS = RW32_BLOCKS * 4;                   // 2512

    for (int l = 0; l < 3; l++) {
        const u16* wqkvC = wbf + (size_t)l * 1048576 + 0;
        const u16* wocat = wbf + (size_t)l * 1048576 + 393216;
        const u16* w1T   = wbf + (size_t)l * 1048576 + 524288;
        const u16* w2T   = wbf + (size_t)l * 1048576 + 786432;

        // fused qkv GEMM (loc|exp), 32-row rw, split-store q / k|v (pre-permuted)
        qkv_rw<<<QKV_BLOCKS, 256, 0, stream>>>(
            h_b, wqkvC, bcat + l * 1536,
            qb_loc, kv_loc, qb_exp, kv_exp, NNODES);

        // fused: vn online partials + local + expander edge attention -> acat/part
        attn_fused_kernel<<<ATTN_BLOCKS, 256, 0, stream>>>(
            qb_loc, kv_loc, qb_exp, kv_exp, indptr, srcs, esrcs, acat, part);

        // Wo-cat GEMM + residual + LayerNorm fused (+ inline vn merge in block VN/32):
        // h = LN(h_f + acat@[WoL;WoE] + bsum) -> h_f (f32) + h_b (FM bf16)
        wo_ln_rw<<<RW32_BLOCKS, 256, 0, stream>>>(
            acat, wocat, bsum + l * 256, h_f,
            ln_g + l * 256, ln_b + l * 256, h_f, h_b, part, acat, NNODES);

        // FFN: mid = gelu(h@W1+b1), 32-row rw (2512 blocks)
        ffn1_rw<<<FFN1_BLOCKS, 256, 0, stream>>>(
            h_b, w1T, b1 + l * 1024, mid, NNODES);

        // h += mid@W2 + b2 (A read once; fused residual)
        if (l < 2) {
            w2_rw<<<RW32_BLOCKS, 256, 0, stream>>>(
                mid, w2T, b2 + l * 256, h_f, h_f, h_b, 0, NNODES);
        } else {
            w2_rw<<<RW32_BLOCKS, 256, 0, stream>>>(
                mid, w2T, b2 + l * 256, h_f, (float*)d_out, nullptr, 1, NNODES);
        }
    }
}